// Round 3
// baseline (1473.775 us; speedup 1.0000x reference)
//
#include <hip/hip_runtime.h>
#include <math.h>

// Kalman filter, restructured around batch-independence of the covariance
// recursion: P_t, S_t, K_t are identical for all batches (cov0 is the same
// broadcast matrix per batch; F,H,Q,R shared). Kernel 1 (one block) computes
// the shared trajectory in FP64 with partial-pivoted Gauss-Jordan and emits
// M_t = (I - K_t H) F (32x32) and K_t (32x16) as fp32 into d_ws.
// Kernel 2 runs the per-batch affine recursion x_{t+1} = M_t x_t + K_t z_t
// in fp32 (stable map) and writes out (B,T,32) fp32.

#define S_DIM 32
#define O_DIM 16
#define MK_STRIDE 1536   // 1024 (M) + 512 (K) floats per step

// ---------------- Kernel 1: shared trajectory (fp64) ----------------
__global__ __launch_bounds__(256) void traj_kernel(
    const float* __restrict__ cov0,  // (B,32,32) -> use batch 0
    const float* __restrict__ Fm,    // (32,32)
    const float* __restrict__ Hm,    // (16,32)
    const float* __restrict__ Qm,    // (32,32)
    const float* __restrict__ Rm,    // (16,16)
    float* __restrict__ wsMK,        // (T,1536)
    int T)
{
    __shared__ double P [S_DIM*33];
    __shared__ double Fs[S_DIM*33];
    __shared__ double Qs[S_DIM*33];
    __shared__ double Hs[O_DIM*33];
    __shared__ double Rs[O_DIM*17];
    __shared__ double HP[O_DIM*33];
    __shared__ double A [O_DIM*33];   // augmented [S | I]
    __shared__ double Kg[S_DIM*17];
    __shared__ double W [S_DIM*33];   // I - K H
    __shared__ double T2[S_DIM*33];   // (I-KH)F when F != I
    __shared__ double fcol[O_DIM];
    __shared__ int piv, notId;

    const int tid = threadIdx.x;

    for (int i = tid; i < S_DIM*S_DIM; i += 256) {
        int r = i >> 5, c = i & 31;
        P [r*33+c] = (double)cov0[i];   // batch 0's initial covariance
        Fs[r*33+c] = (double)Fm[i];
        Qs[r*33+c] = (double)Qm[i];
    }
    for (int i = tid; i < O_DIM*S_DIM; i += 256) {
        int r = i >> 5, c = i & 31;
        Hs[r*33+c] = (double)Hm[i];
    }
    for (int i = tid; i < O_DIM*O_DIM; i += 256) {
        int r = i >> 4, c = i & 15;
        Rs[r*17+c] = (double)Rm[i];
    }
    if (tid == 0) notId = 0;
    __syncthreads();

    {   // detect F == I (block-uniform, deterministic)
        bool bad = false;
        for (int i = tid; i < S_DIM*S_DIM; i += 256) {
            int r = i >> 5, c = i & 31;
            if (Fs[r*33+c] != ((r == c) ? 1.0 : 0.0)) bad = true;
        }
        if (bad) notId = 1;
    }
    __syncthreads();
    const bool fId = (notId == 0);

    for (int t = 0; t < T; ++t) {
        // ---- predict: P = F P F^T + Q ----
        if (fId) {
            for (int i = tid; i < S_DIM*S_DIM; i += 256) {
                int r = i >> 5, c = i & 31;
                P[r*33+c] += Qs[r*33+c];
            }
            __syncthreads();
        } else {
            for (int i = tid; i < S_DIM*S_DIM; i += 256) {
                int r = i >> 5, c = i & 31;
                double a = 0.0;
                for (int k = 0; k < S_DIM; ++k) a += Fs[r*33+k]*P[k*33+c];
                W[r*33+c] = a;
            }
            __syncthreads();
            for (int i = tid; i < S_DIM*S_DIM; i += 256) {
                int r = i >> 5, c = i & 31;
                double a = Qs[r*33+c];
                for (int k = 0; k < S_DIM; ++k) a += W[r*33+k]*Fs[c*33+k];
                P[r*33+c] = a;
            }
            __syncthreads();
        }

        // ---- HP = H P  (16x32) ----
        for (int i = tid; i < O_DIM*S_DIM; i += 256) {
            int r = i >> 5, c = i & 31;
            double a = 0.0;
            for (int k = 0; k < S_DIM; ++k) a += Hs[r*33+k]*P[k*33+c];
            HP[r*33+c] = a;
        }
        __syncthreads();

        // ---- A = [S | I],  S = HP H^T + R ----
        for (int i = tid; i < O_DIM*S_DIM; i += 256) {
            int r = i >> 5, c = i & 31;
            double v;
            if (c < O_DIM) {
                double a = Rs[r*17+c];
                for (int k = 0; k < S_DIM; ++k) a += HP[r*33+k]*Hs[c*33+k];
                v = a;
            } else {
                v = ((c - O_DIM) == r) ? 1.0 : 0.0;
            }
            A[r*33+c] = v;
        }
        __syncthreads();

        // ---- Gauss-Jordan with partial pivoting (fp64) ----
        for (int p = 0; p < O_DIM; ++p) {
            if (tid == 0) {
                int best = p; double bv = fabs(A[p*33+p]);
                for (int r = p+1; r < O_DIM; ++r) {
                    double v = fabs(A[r*33+p]);
                    if (v > bv) { bv = v; best = r; }
                }
                piv = best;
            }
            __syncthreads();
            int pv = piv;
            if (pv != p && tid < S_DIM) {
                double tmp = A[p*33+tid];
                A[p*33+tid]  = A[pv*33+tid];
                A[pv*33+tid] = tmp;
            }
            __syncthreads();
            if (tid < O_DIM) fcol[tid] = A[tid*33+p];
            __syncthreads();
            double pinv = 1.0 / fcol[p];
            if (tid < S_DIM) A[p*33+tid] *= pinv;
            __syncthreads();
            for (int i = tid; i < O_DIM*S_DIM; i += 256) {
                int r = i >> 5, c = i & 31;
                if (r != p) A[r*33+c] -= fcol[r]*A[p*33+c];
            }
            __syncthreads();
        }
        // S^{-1} in A[:, 16:32]

        // ---- K = (HP)^T Sinv  (32x16) ----
        for (int i = tid; i < S_DIM*O_DIM; i += 256) {
            int r = i >> 4, c = i & 15;
            double a = 0.0;
            for (int k = 0; k < O_DIM; ++k) a += HP[k*33+r]*A[k*33+O_DIM+c];
            Kg[r*17+c] = a;
        }
        __syncthreads();

        // ---- W = I - K H ----
        for (int i = tid; i < S_DIM*S_DIM; i += 256) {
            int r = i >> 5, c = i & 31;
            double a = (r == c) ? 1.0 : 0.0;
            for (int k = 0; k < O_DIM; ++k) a -= Kg[r*17+k]*Hs[k*33+c];
            W[r*33+c] = a;
        }
        __syncthreads();

        // ---- M = W F (general) or W (F == I) ----
        if (!fId) {
            for (int i = tid; i < S_DIM*S_DIM; i += 256) {
                int r = i >> 5, c = i & 31;
                double a = 0.0;
                for (int k = 0; k < S_DIM; ++k) a += W[r*33+k]*Fs[k*33+c];
                T2[r*33+c] = a;
            }
            __syncthreads();
        }
        const double* M = fId ? W : T2;

        // ---- emit M, K as fp32 ----
        float* MK = wsMK + (long)t * MK_STRIDE;
        for (int i = tid; i < S_DIM*S_DIM; i += 256) {
            int r = i >> 5, c = i & 31;
            MK[i] = (float)M[r*33+c];
        }
        for (int i = tid; i < S_DIM*O_DIM; i += 256) {
            int r = i >> 4, c = i & 15;
            MK[1024 + i] = (float)Kg[r*17+c];
        }

        // ---- P = P - K HP ----
        for (int i = tid; i < S_DIM*S_DIM; i += 256) {
            int r = i >> 5, c = i & 31;
            double a = 0.0;
            for (int k = 0; k < O_DIM; ++k) a += Kg[r*17+k]*HP[k*33+c];
            P[r*33+c] -= a;
        }
        __syncthreads();
    }
}

// ---------------- Kernel 2: per-batch affine recursion (fp32) ----------------
// 8 batches per 256-thread block; thread (bb = tid>>5, s = tid&31).
__global__ __launch_bounds__(256) void batch_kernel(
    const float* __restrict__ state0,  // (B,32)
    const float* __restrict__ meas,    // (B,T,16)
    const float* __restrict__ wsMK,    // (T,1536)
    float* __restrict__ out,           // (B,T,32)
    int T)
{
    __shared__ float Ms[S_DIM*33];
    __shared__ float Ks[S_DIM*17];
    __shared__ float Xs[8*33];
    __shared__ float Zs[8*O_DIM];

    const int tid = threadIdx.x;
    const int b0  = blockIdx.x * 8;
    const int bb  = tid >> 5;
    const int s   = tid & 31;

    Xs[bb*33+s] = state0[(long)(b0+bb)*S_DIM + s];
    __syncthreads();

    for (int t = 0; t < T; ++t) {
        const float* MK = wsMK + (long)t * MK_STRIDE;
        for (int i = tid; i < S_DIM*S_DIM; i += 256) {
            int r = i >> 5, c = i & 31;
            Ms[r*33+c] = MK[i];
        }
        for (int i = tid; i < S_DIM*O_DIM; i += 256) {
            int r = i >> 4, c = i & 15;
            Ks[r*17+c] = MK[1024 + i];
        }
        if (tid < 8*O_DIM) {
            int q = tid >> 4, k = tid & 15;
            Zs[q*O_DIM+k] = meas[((long)(b0+q)*T + t)*O_DIM + k];
        }
        __syncthreads();

        float acc = 0.f;
        for (int j = 0; j < S_DIM; ++j) acc += Ms[s*33+j]*Xs[bb*33+j];
        for (int k = 0; k < O_DIM; ++k) acc += Ks[s*17+k]*Zs[bb*O_DIM+k];

        out[((long)(b0+bb)*T + t)*S_DIM + s] = acc;
        __syncthreads();          // all reads of Xs done
        Xs[bb*33+s] = acc;
        __syncthreads();          // writes visible before next step
    }
}

extern "C" void kernel_launch(void* const* d_in, const int* in_sizes, int n_in,
                              void* d_out, int out_size, void* d_ws, size_t ws_size,
                              hipStream_t stream) {
    const float* state0 = (const float*)d_in[0];
    const float* cov0   = (const float*)d_in[1];
    const float* meas   = (const float*)d_in[2];
    const float* Fm     = (const float*)d_in[3];
    const float* Hm     = (const float*)d_in[4];
    const float* Qm     = (const float*)d_in[5];
    const float* Rm     = (const float*)d_in[6];
    float* out   = (float*)d_out;
    float* wsMK  = (float*)d_ws;

    const int B = in_sizes[0] / S_DIM;               // 2048
    const int T = in_sizes[2] / (B * O_DIM);         // 64

    traj_kernel<<<dim3(1), dim3(256), 0, stream>>>(cov0, Fm, Hm, Qm, Rm, wsMK, T);
    batch_kernel<<<dim3(B/8), dim3(256), 0, stream>>>(state0, meas, wsMK, out, T);
}

// Round 4
// 573.876 us; speedup vs baseline: 2.5681x; 2.5681x over previous
//
#include <hip/hip_runtime.h>
#include <math.h>

// Kalman filter. Covariance trajectory (P_t, K_t) is batch-independent:
//   Kernel 1 (traj): 1 block, fp64, serial over T. No-pivot Gauss-Jordan
//     (S is SPD), 2 barriers/pivot. Emits K_t (fp32) to ws.
//   Kernel 2 (mk):   T blocks, computes M_t = (I - K_t H) F (fp32) to ws.
//   Kernel 3 (batch): B/8 blocks, fp32 affine recursion x = M x + K z.

#define S_DIM 32
#define O_DIM 16
#define MK_STRIDE 1536   // per step: 1024 floats M + 512 floats K

// ---------------- Kernel 1: shared trajectory (fp64, 1 block) ----------------
__global__ __launch_bounds__(256) void traj_kernel(
    const float* __restrict__ cov0,  // (B,32,32) -> batch 0
    const float* __restrict__ Fm,    // (32,32)
    const float* __restrict__ Hm,    // (16,32)
    const float* __restrict__ Qm,    // (32,32)
    const float* __restrict__ Rm,    // (16,16)
    float* __restrict__ wsMK,        // (T,1536)
    int T)
{
    __shared__ double P [S_DIM*33];
    __shared__ double Fs[S_DIM*33];
    __shared__ double Qs[S_DIM*33];
    __shared__ double Hs[O_DIM*33];
    __shared__ double Rs[O_DIM*17];
    __shared__ double HP[O_DIM*33];
    __shared__ double A [O_DIM*33];   // augmented [S | I]
    __shared__ double Kg[S_DIM*17];
    __shared__ double Tp[S_DIM*33];   // temp for F*P (general-F path)
    __shared__ int notId;

    const int tid = threadIdx.x;

    for (int i = tid; i < S_DIM*S_DIM; i += 256) {
        int r = i >> 5, c = i & 31;
        P [r*33+c] = (double)cov0[i];
        Fs[r*33+c] = (double)Fm[i];
        Qs[r*33+c] = (double)Qm[i];
    }
    for (int i = tid; i < O_DIM*S_DIM; i += 256) {
        int r = i >> 5, c = i & 31;
        Hs[r*33+c] = (double)Hm[i];
    }
    for (int i = tid; i < O_DIM*O_DIM; i += 256) {
        int r = i >> 4, c = i & 15;
        Rs[r*17+c] = (double)Rm[i];
    }
    if (tid == 0) notId = 0;
    __syncthreads();

    {   // F == I detection (block-uniform)
        bool bad = false;
        for (int i = tid; i < S_DIM*S_DIM; i += 256) {
            int r = i >> 5, c = i & 31;
            if (Fs[r*33+c] != ((r == c) ? 1.0 : 0.0)) bad = true;
        }
        if (bad) notId = 1;
    }
    __syncthreads();
    const bool fId = (notId == 0);

    for (int t = 0; t < T; ++t) {
        // ---- predict: P = F P F^T + Q ----
        if (fId) {
            for (int i = tid; i < S_DIM*S_DIM; i += 256) {
                int r = i >> 5, c = i & 31;
                P[r*33+c] += Qs[r*33+c];
            }
            __syncthreads();
        } else {
            for (int i = tid; i < S_DIM*S_DIM; i += 256) {
                int r = i >> 5, c = i & 31;
                double a = 0.0;
                for (int k = 0; k < S_DIM; ++k) a += Fs[r*33+k]*P[k*33+c];
                Tp[r*33+c] = a;
            }
            __syncthreads();
            for (int i = tid; i < S_DIM*S_DIM; i += 256) {
                int r = i >> 5, c = i & 31;
                double a = Qs[r*33+c];
                for (int k = 0; k < S_DIM; ++k) a += Tp[r*33+k]*Fs[c*33+k];
                P[r*33+c] = a;
            }
            __syncthreads();
        }

        // ---- HP = H P (16x32): 2 elements/thread ----
        {
            int i0 = tid, i1 = tid + 256;
            int r0 = i0 >> 5, c0 = i0 & 31;
            int r1 = i1 >> 5, c1 = i1 & 31;
            double a0 = 0.0, a1 = 0.0;
            for (int k = 0; k < S_DIM; ++k) {
                a0 += Hs[r0*33+k]*P[k*33+c0];
                a1 += Hs[r1*33+k]*P[k*33+c1];
            }
            HP[r0*33+c0] = a0;
            HP[r1*33+c1] = a1;
        }
        __syncthreads();

        // ---- A = [S | I], S = HP H^T + R ----
        {
            int i0 = tid, i1 = tid + 256;
            int r0 = i0 >> 5, c0 = i0 & 31;
            int r1 = i1 >> 5, c1 = i1 & 31;
            double v0, v1;
            if (c0 < O_DIM) {
                double a = Rs[r0*17+c0];
                for (int k = 0; k < S_DIM; ++k) a += HP[r0*33+k]*Hs[c0*33+k];
                v0 = a;
            } else v0 = ((c0 - O_DIM) == r0) ? 1.0 : 0.0;
            if (c1 < O_DIM) {
                double a = Rs[r1*17+c1];
                for (int k = 0; k < S_DIM; ++k) a += HP[r1*33+k]*Hs[c1*33+k];
                v1 = a;
            } else v1 = ((c1 - O_DIM) == r1) ? 1.0 : 0.0;
            A[r0*33+c0] = v0;
            A[r1*33+c1] = v1;
        }
        __syncthreads();

        // ---- Gauss-Jordan, NO pivoting (S is SPD), 2 barriers/pivot ----
        // Thread handles elements tid and tid+256: same c, rows r0 and r0+8.
        {
            const int r0 = tid >> 5, c = tid & 31;
            const int r1 = r0 + 8;
            for (int p = 0; p < O_DIM; ++p) {
                double a_r0c = A[r0*33+c];
                double a_r1c = A[r1*33+c];
                double a_r0p = A[r0*33+p];
                double a_r1p = A[r1*33+p];
                double a_pc  = A[p*33+c];
                double app   = A[p*33+p];
                __syncthreads();
                double pinv = 1.0 / app;
                double sc   = a_pc * pinv;
                A[r0*33+c] = (r0 == p) ? sc : a_r0c - a_r0p * sc;
                A[r1*33+c] = (r1 == p) ? sc : a_r1c - a_r1p * sc;
                __syncthreads();
            }
        }
        // S^{-1} in A[:, 16:32]

        // ---- K = (HP)^T Sinv (32x16): 2 elements/thread ----
        {
            int i0 = tid, i1 = tid + 256;
            int r0 = i0 >> 4, c0 = i0 & 15;
            int r1 = i1 >> 4, c1 = i1 & 15;
            double a0 = 0.0, a1 = 0.0;
            for (int k = 0; k < O_DIM; ++k) {
                a0 += HP[k*33+r0]*A[k*33+O_DIM+c0];
                a1 += HP[k*33+r1]*A[k*33+O_DIM+c1];
            }
            Kg[r0*17+c0] = a0;
            Kg[r1*17+c1] = a1;
        }
        __syncthreads();

        // ---- emit K (fp32) + P = P - K HP ----
        {
            float* MK = wsMK + (long)t * MK_STRIDE;
            int i0 = tid, i1 = tid + 256;
            MK[1024 + i0] = (float)Kg[(i0 >> 4)*17 + (i0 & 15)];
            MK[1024 + i1] = (float)Kg[(i1 >> 4)*17 + (i1 & 15)];
            for (int i = tid; i < S_DIM*S_DIM; i += 256) {
                int r = i >> 5, c = i & 31;
                double a = 0.0;
                for (int k = 0; k < O_DIM; ++k) a += Kg[r*17+k]*HP[k*33+c];
                P[r*33+c] -= a;
            }
        }
        __syncthreads();
    }
}

// ---------------- Kernel 2: M_t = (I - K_t H) F, fp32, T blocks ----------------
__global__ __launch_bounds__(256) void mk_kernel(
    const float* __restrict__ Fm,    // (32,32)
    const float* __restrict__ Hm,    // (16,32)
    float* __restrict__ wsMK,        // (T,1536): K at +1024 (in), M at +0 (out)
    int T)
{
    __shared__ float Kl[S_DIM*17];
    __shared__ float Hl[O_DIM*33];
    __shared__ float Fl[S_DIM*33];
    __shared__ float Wl[S_DIM*33];
    __shared__ int notId;

    const int tid = threadIdx.x;
    const int t   = blockIdx.x;
    float* MK = wsMK + (long)t * MK_STRIDE;

    for (int i = tid; i < S_DIM*O_DIM; i += 256)
        Kl[(i >> 4)*17 + (i & 15)] = MK[1024 + i];
    for (int i = tid; i < O_DIM*S_DIM; i += 256)
        Hl[(i >> 5)*33 + (i & 31)] = Hm[i];
    for (int i = tid; i < S_DIM*S_DIM; i += 256)
        Fl[(i >> 5)*33 + (i & 31)] = Fm[i];
    if (tid == 0) notId = 0;
    __syncthreads();
    {
        bool bad = false;
        for (int i = tid; i < S_DIM*S_DIM; i += 256) {
            int r = i >> 5, c = i & 31;
            if (Fl[r*33+c] != ((r == c) ? 1.0f : 0.0f)) bad = true;
        }
        if (bad) notId = 1;
    }
    __syncthreads();
    const bool fId = (notId == 0);

    if (fId) {
        for (int i = tid; i < S_DIM*S_DIM; i += 256) {
            int r = i >> 5, c = i & 31;
            float a = (r == c) ? 1.0f : 0.0f;
            for (int k = 0; k < O_DIM; ++k) a -= Kl[r*17+k]*Hl[k*33+c];
            MK[i] = a;
        }
    } else {
        for (int i = tid; i < S_DIM*S_DIM; i += 256) {
            int r = i >> 5, c = i & 31;
            float a = (r == c) ? 1.0f : 0.0f;
            for (int k = 0; k < O_DIM; ++k) a -= Kl[r*17+k]*Hl[k*33+c];
            Wl[r*33+c] = a;
        }
        __syncthreads();
        for (int i = tid; i < S_DIM*S_DIM; i += 256) {
            int r = i >> 5, c = i & 31;
            float a = 0.0f;
            for (int k = 0; k < S_DIM; ++k) a += Wl[r*33+k]*Fl[k*33+c];
            MK[i] = a;
        }
    }
}

// ---------------- Kernel 3: per-batch affine recursion (fp32) ----------------
__global__ __launch_bounds__(256) void batch_kernel(
    const float* __restrict__ state0,  // (B,32)
    const float* __restrict__ meas,    // (B,T,16)
    const float* __restrict__ wsMK,    // (T,1536)
    float* __restrict__ out,           // (B,T,32)
    int T)
{
    __shared__ float Ms[S_DIM*33];
    __shared__ float Ks[S_DIM*17];
    __shared__ float Xs[2][8*33];
    __shared__ float Zs[8*O_DIM];

    const int tid = threadIdx.x;
    const int b0  = blockIdx.x * 8;
    const int bb  = tid >> 5;
    const int s   = tid & 31;

    Xs[0][bb*33+s] = state0[(long)(b0+bb)*S_DIM + s];
    int cur = 0;

    for (int t = 0; t < T; ++t) {
        const float* MK = wsMK + (long)t * MK_STRIDE;
        for (int i = tid; i < S_DIM*S_DIM; i += 256)
            Ms[(i >> 5)*33 + (i & 31)] = MK[i];
        for (int i = tid; i < S_DIM*O_DIM; i += 256)
            Ks[(i >> 4)*17 + (i & 15)] = MK[1024 + i];
        if (tid < 8*O_DIM) {
            int q = tid >> 4, k = tid & 15;
            Zs[q*O_DIM+k] = meas[((long)(b0+q)*T + t)*O_DIM + k];
        }
        __syncthreads();

        float acc = 0.f;
        for (int j = 0; j < S_DIM; ++j) acc += Ms[s*33+j]*Xs[cur][bb*33+j];
        for (int k = 0; k < O_DIM; ++k) acc += Ks[s*17+k]*Zs[bb*O_DIM+k];

        out[((long)(b0+bb)*T + t)*S_DIM + s] = acc;
        Xs[cur^1][bb*33+s] = acc;
        cur ^= 1;
        __syncthreads();
    }
}

extern "C" void kernel_launch(void* const* d_in, const int* in_sizes, int n_in,
                              void* d_out, int out_size, void* d_ws, size_t ws_size,
                              hipStream_t stream) {
    const float* state0 = (const float*)d_in[0];
    const float* cov0   = (const float*)d_in[1];
    const float* meas   = (const float*)d_in[2];
    const float* Fm     = (const float*)d_in[3];
    const float* Hm     = (const float*)d_in[4];
    const float* Qm     = (const float*)d_in[5];
    const float* Rm     = (const float*)d_in[6];
    float* out   = (float*)d_out;
    float* wsMK  = (float*)d_ws;

    const int B = in_sizes[0] / S_DIM;               // 2048
    const int T = in_sizes[2] / (B * O_DIM);         // 64

    traj_kernel<<<dim3(1), dim3(256), 0, stream>>>(cov0, Fm, Hm, Qm, Rm, wsMK, T);
    mk_kernel<<<dim3(T), dim3(256), 0, stream>>>(Fm, Hm, wsMK, T);
    batch_kernel<<<dim3(B/8), dim3(256), 0, stream>>>(state0, meas, wsMK, out, T);
}